// Round 1
// baseline (411.367 us; speedup 1.0000x reference)
//
#include <hip/hip_runtime.h>
#include <math.h>

#define NSEG 129
#define NGROUP 128
#define NIMG 4

// ALPHA=10, BETA=2 ; C = ALPHA - ALPHA*ln(1+ALPHA/BETA) = 10 - 10*ln(6)
#define WING_C (-7.917594692280550f)

// ---------------------------------------------------------------------------
// Pass 1: per-(img,seg) counts and sums via per-block LDS histogram.
// grid = (blocksX, NIMG), block = 256
__global__ __launch_bounds__(256) void accum_kernel(const float4* __restrict__ pred,
                                                    const int* __restrict__ gt,
                                                    float* __restrict__ counts,
                                                    float* __restrict__ sums,
                                                    int n) {
    __shared__ float s_cnt[NSEG];
    __shared__ float s_sum[NSEG * 4];
    const int img = blockIdx.y;
    for (int i = threadIdx.x; i < NSEG; i += 256) s_cnt[i] = 0.f;
    for (int i = threadIdx.x; i < NSEG * 4; i += 256) s_sum[i] = 0.f;
    __syncthreads();

    const float4* p = pred + (size_t)img * n;
    const int* g = gt + (size_t)img * n;
    for (int i = blockIdx.x * 256 + threadIdx.x; i < n; i += gridDim.x * 256) {
        int seg = g[i] + 1;
        seg = max(0, min(NSEG - 1, seg));
        float4 v = p[i];
        atomicAdd(&s_cnt[seg], 1.f);
        atomicAdd(&s_sum[seg * 4 + 0], v.x);
        atomicAdd(&s_sum[seg * 4 + 1], v.y);
        atomicAdd(&s_sum[seg * 4 + 2], v.z);
        atomicAdd(&s_sum[seg * 4 + 3], v.w);
    }
    __syncthreads();

    for (int i = threadIdx.x; i < NSEG; i += 256) {
        float c = s_cnt[i];
        if (c != 0.f) {
            atomicAdd(&counts[img * NSEG + i], c);
            atomicAdd(&sums[(img * NSEG + i) * 4 + 0], s_sum[i * 4 + 0]);
            atomicAdd(&sums[(img * NSEG + i) * 4 + 1], s_sum[i * 4 + 1]);
            atomicAdd(&sums[(img * NSEG + i) * 4 + 2], s_sum[i * 4 + 2]);
            atomicAdd(&sums[(img * NSEG + i) * 4 + 3], s_sum[i * 4 + 3]);
        }
    }
}

// ---------------------------------------------------------------------------
// Pass 2: means = sums / max(counts, 1)
__global__ __launch_bounds__(256) void means_kernel(const float* __restrict__ counts,
                                                    const float* __restrict__ sums,
                                                    float* __restrict__ means) {
    int idx = blockIdx.x * 256 + threadIdx.x;  // over NIMG*NSEG
    if (idx < NIMG * NSEG) {
        float c = fmaxf(counts[idx], 1.f);
        means[idx * 4 + 0] = sums[idx * 4 + 0] / c;
        means[idx * 4 + 1] = sums[idx * 4 + 1] / c;
        means[idx * 4 + 2] = sums[idx * 4 + 2] / c;
        means[idx * 4 + 3] = sums[idx * 4 + 3] / c;
    }
}

// ---------------------------------------------------------------------------
// Pass 3: wing loss per element against means[seg]; segment-sum via LDS.
__global__ __launch_bounds__(256) void wl_kernel(const float4* __restrict__ pred,
                                                 const int* __restrict__ gt,
                                                 const float* __restrict__ means,
                                                 float* __restrict__ wlsum,
                                                 int n) {
    __shared__ float s_mean[NSEG * 4];
    __shared__ float s_wl[NSEG];
    const int img = blockIdx.y;
    for (int i = threadIdx.x; i < NSEG * 4; i += 256) s_mean[i] = means[img * NSEG * 4 + i];
    for (int i = threadIdx.x; i < NSEG; i += 256) s_wl[i] = 0.f;
    __syncthreads();

    const float4* p = pred + (size_t)img * n;
    const int* g = gt + (size_t)img * n;
    for (int i = blockIdx.x * 256 + threadIdx.x; i < n; i += gridDim.x * 256) {
        int seg = g[i] + 1;
        seg = max(0, min(NSEG - 1, seg));
        float4 v = p[i];
        float d0 = fabsf(v.x - s_mean[seg * 4 + 0]);
        float d1 = fabsf(v.y - s_mean[seg * 4 + 1]);
        float d2 = fabsf(v.z - s_mean[seg * 4 + 2]);
        float d3 = fabsf(v.w - s_mean[seg * 4 + 3]);
        float w = 0.f;
        w += (d0 < 10.f) ? 10.f * log1pf(d0 * 0.5f) : (d0 - WING_C);
        w += (d1 < 10.f) ? 10.f * log1pf(d1 * 0.5f) : (d1 - WING_C);
        w += (d2 < 10.f) ? 10.f * log1pf(d2 * 0.5f) : (d2 - WING_C);
        w += (d3 < 10.f) ? 10.f * log1pf(d3 * 0.5f) : (d3 - WING_C);
        atomicAdd(&s_wl[seg], w);
    }
    __syncthreads();

    for (int i = threadIdx.x; i < NSEG; i += 256) {
        float w = s_wl[i];
        if (w != 0.f) atomicAdd(&wlsum[img * NSEG + i], w);
    }
}

// ---------------------------------------------------------------------------
// Pass 4: per-image pull + push, averaged. Single block.
__global__ __launch_bounds__(256) void final_kernel(const float* __restrict__ counts,
                                                    const float* __restrict__ wlsum,
                                                    const float* __restrict__ means,
                                                    float* __restrict__ out) {
    __shared__ float s_tag[NGROUP * 4];
    __shared__ float s_valid[NGROUP];
    __shared__ float s_num, s_pull, s_push, s_total;
    const int t = threadIdx.x;
    if (t == 0) s_total = 0.f;

    for (int img = 0; img < NIMG; ++img) {
        if (t == 0) { s_num = 0.f; s_pull = 0.f; s_push = 0.f; }
        __syncthreads();
        // load tags + valid, count num
        for (int gi = t; gi < NGROUP; gi += 256) {
            float c = counts[img * NSEG + gi + 1];
            float v = (c > 0.f) ? 1.f : 0.f;
            s_valid[gi] = v;
            s_tag[gi * 4 + 0] = means[(img * NSEG + gi + 1) * 4 + 0];
            s_tag[gi * 4 + 1] = means[(img * NSEG + gi + 1) * 4 + 1];
            s_tag[gi * 4 + 2] = means[(img * NSEG + gi + 1) * 4 + 2];
            s_tag[gi * 4 + 3] = means[(img * NSEG + gi + 1) * 4 + 3];
            if (v != 0.f) atomicAdd(&s_num, 1.f);
        }
        __syncthreads();
        const float num = s_num;

        // pull partials
        float pp = 0.f;
        for (int gi = t; gi < NGROUP; gi += 256) {
            float c = counts[img * NSEG + gi + 1];
            float gw = wlsum[img * NSEG + gi + 1] / fmaxf(c * 4.f, 1.f);
            pp += gw * s_valid[gi];
        }
        // push partials (128x128 pairs incl. diagonal; subtract num below)
        float ps = 0.f;
        for (int idx = t; idx < NGROUP * NGROUP; idx += 256) {
            int a = idx >> 7, b = idx & (NGROUP - 1);
            float dx = s_tag[a * 4 + 0] - s_tag[b * 4 + 0];
            float dy = s_tag[a * 4 + 1] - s_tag[b * 4 + 1];
            float dz = s_tag[a * 4 + 2] - s_tag[b * 4 + 2];
            float dw = s_tag[a * 4 + 3] - s_tag[b * 4 + 3];
            float d2 = dx * dx + dy * dy + dz * dz + dw * dw;
            ps += expf(-d2) * s_valid[a] * s_valid[b];
        }
        atomicAdd(&s_pull, pp);
        atomicAdd(&s_push, ps);
        __syncthreads();
        if (t == 0) {
            float pull = s_pull / (num + 1e-6f);
            float push = (s_push - num) / ((num - 1.f) * num + 1e-6f) * 0.5f;
            s_total += push + pull;
        }
        __syncthreads();
    }
    if (t == 0) out[0] = s_total * (1.f / NIMG);
}

// ---------------------------------------------------------------------------
extern "C" void kernel_launch(void* const* d_in, const int* in_sizes, int n_in,
                              void* d_out, int out_size, void* d_ws, size_t ws_size,
                              hipStream_t stream) {
    const float4* pred = (const float4*)d_in[0];
    const int* gt = (const int*)d_in[1];
    // d_in[2] (anchor_inds) is unused by the reference.
    const int n_per_img = in_sizes[1] / NIMG;  // 2,000,000

    float* ws = (float*)d_ws;
    float* counts = ws;                         // NIMG*NSEG           = 516
    float* sums   = ws + 516;                   // NIMG*NSEG*4         = 2064
    float* wlsum  = ws + 516 + 2064;            // NIMG*NSEG           = 516
    float* means  = ws + 516 + 2064 + 516;      // NIMG*NSEG*4         = 2064

    // zero the accumulators (ws is poisoned 0xAA and never re-poisoned)
    hipMemsetAsync(d_ws, 0, (size_t)(516 + 2064 + 516) * sizeof(float), stream);

    dim3 grid(256, NIMG);
    accum_kernel<<<grid, 256, 0, stream>>>(pred, gt, counts, sums, n_per_img);
    means_kernel<<<3, 256, 0, stream>>>(counts, sums, means);
    wl_kernel<<<grid, 256, 0, stream>>>(pred, gt, means, wlsum, n_per_img);
    final_kernel<<<1, 256, 0, stream>>>(counts, wlsum, means, (float*)d_out);
}